// Round 5
// baseline (326.123 us; speedup 1.0000x reference)
//
#include <hip/hip_runtime.h>
#include <stdint.h>

#define N_V 50000
#define F_DIM 128
#define K_DIM 128
#define H_DIM 3
#define M_DIM 10

using bf16x8 = __attribute__((ext_vector_type(8))) short;  // 8 bf16 = 4 VGPRs
using f32x4  = __attribute__((ext_vector_type(4))) float;

__device__ inline unsigned short f2bf(float f) {
    union { float f; uint32_t u; } v; v.f = f;
    uint32_t u = v.u;
    u += 0x7fffu + ((u >> 16) & 1u);   // round-to-nearest-even
    return (unsigned short)(u >> 16);
}

#define LDS_AS __attribute__((address_space(3)))
__device__ inline void gl2lds16(const void* g, void* l) {
    __builtin_amdgcn_global_load_lds(
        (const __attribute__((address_space(1))) unsigned int*)g,
        (LDS_AS unsigned int*)l, 16, 0, 0);
}

// ---------------------------------------------------------------------------
// Kernel 1 (prep): three segments.
//  a) weights (H,F,K) fp32 -> Wt[b][k][f] bf16 (f contiguous)
//  b) X fp32 -> Xb bf16 row-major
//  c) wa[b][f] = sum_col W_b[f,col] * a_vec_b[col]  -> bf16  (for e = X*wa)
// ---------------------------------------------------------------------------
#define WTOT (9 * 128 * 128)
#define XCH  (N_V * 16)          /* 8-element chunks of X */
#define WACT (9 * 128)

__global__ void prep(const float* __restrict__ Wvc,
                     const float* __restrict__ Wvn_int,
                     const float* __restrict__ Wvn_nh,
                     const float* __restrict__ X,
                     const float* __restrict__ a,
                     unsigned short* __restrict__ Wt,
                     unsigned short* __restrict__ Xb,
                     unsigned short* __restrict__ wab) {
    int idx = blockIdx.x * 256 + threadIdx.x;
    if (idx < WTOT) {
        int b   = idx >> 14;
        int rem = idx & 16383;
        int k = rem >> 7;
        int f = rem & 127;
        int h = b / 3, t = b - 3 * h;
        const float* src = (t == 0) ? Wvc : (t == 1) ? Wvn_int : Wvn_nh;
        Wt[idx] = f2bf(src[(h * 128 + f) * 128 + k]);
        return;
    }
    int xi = idx - WTOT;             // chunk of 8 floats of X
    if (xi < XCH) {
        const float4* Xv = (const float4*)X;
        float4 v0 = Xv[xi * 2];
        float4 v1 = Xv[xi * 2 + 1];
        uint4 o;
        o.x = (uint32_t)f2bf(v0.x) | ((uint32_t)f2bf(v0.y) << 16);
        o.y = (uint32_t)f2bf(v0.z) | ((uint32_t)f2bf(v0.w) << 16);
        o.z = (uint32_t)f2bf(v1.x) | ((uint32_t)f2bf(v1.y) << 16);
        o.w = (uint32_t)f2bf(v1.z) | ((uint32_t)f2bf(v1.w) << 16);
        *(uint4*)&Xb[(size_t)xi * 8] = o;
        return;
    }
    int wi = xi - XCH;               // wa entry
    if (wi < WACT) {
        int b = wi >> 7, f = wi & 127;
        int h = b / 3, t = b - 3 * h;
        const float* src = (t == 0) ? Wvc : (t == 1) ? Wvn_int : Wvn_nh;
        const float4* wrow = (const float4*)&src[(h * 128 + f) * 128];
        const float4* av   = (const float4*)&a[h * 256 + (t == 0 ? 128 : 0)];
        float acc = 0.f;
        #pragma unroll 8
        for (int c = 0; c < 32; ++c) {
            float4 w = wrow[c], x = av[c];
            acc += w.x * x.x + w.y * x.y + w.z * x.z + w.w * x.w;
        }
        wab[b * 128 + f] = f2bf(acc);
    }
}

// ---------------------------------------------------------------------------
// Kernel 2: MFMA GEMM. Grid = (ceil(N/64)) = 782 blocks, 256 thr (4 waves).
// Block stages its 64-row A-tile ONCE (global_load_lds 16B, XOR-16 swizzle),
// then loops over all 9 weight blocks b: B-frags direct from global (L2-hot),
// 32 MFMA/wave, pack-2 stores. e = A*wa via MFMA, balanced wave (b%4).
// 782 blocks = one co-resident generation at 3 blocks/CU.
// ---------------------------------------------------------------------------
__global__ __launch_bounds__(256, 3) void gemm_kernel(
    const unsigned short* __restrict__ Xb,  // N_V x 128 bf16
    const unsigned short* __restrict__ Wt,  // 9 x 128(k) x 128(f) bf16
    const unsigned short* __restrict__ wab, // 9 x 128 bf16
    float* __restrict__ out,                // N_V x 384
    unsigned short* __restrict__ Vint,      // H*N_V*128 bf16
    unsigned short* __restrict__ Vnh,      // H*N_V*128 bf16
    float* __restrict__ e_center,           // H*N_V
    float* __restrict__ e_int,
    float* __restrict__ e_nh) {
    __shared__ unsigned short As[64 * 128];   // 16 KB, swizzled

    const int tid    = threadIdx.x;
    const int m_base = blockIdx.x * 64;
    const int wv     = tid >> 6;
    const int lane   = tid & 63;
    const int q      = lane >> 4;
    const int ln     = lane & 15;

    // ---- A staging (once): 1024 chunks of 16B. physical chunk p of row r
    // holds logical chunk p ^ (r & 15); dest = wave-uniform base + lane*16.
    #pragma unroll
    for (int it = 0; it < 4; ++it) {
        int c16 = it * 256 + tid;       // 0..1023
        int r   = c16 >> 4;
        int p   = c16 & 15;
        int lch = p ^ (r & 15);
        int gr  = m_base + r;
        if (gr >= N_V) gr = 0;          // clamp (stores guarded later)
        gl2lds16(Xb + (size_t)gr * 128 + lch * 8, &As[c16 * 8]);
    }
    __syncthreads();

    // ---- pre-load A fragments into registers (reused for all 9 b's)
    bf16x8 afr[4][4];                       // [row-tile][kk]  64 VGPRs
    #pragma unroll
    for (int rt = 0; rt < 4; ++rt) {
        int r = rt * 16 + ln;
        #pragma unroll
        for (int kk = 0; kk < 4; ++kk) {
            int p = (kk * 4 + q) ^ ln;      // unswizzle (r & 15 == ln)
            afr[rt][kk] = *(const bf16x8*)&As[r * 128 + p * 8];
        }
    }

    const int c0 = wv * 32 + 2 * ln;        // thread's adjacent col pair

    for (int b = 0; b < 9; ++b) {
        const int h = b / 3;
        const int t = b - 3 * h;

        // ---- B fragments (direct global, L2-hot). col = wv*32 + 2*ln + ct.
        const unsigned short* Wb = Wt + b * 16384;
        bf16x8 bfr[2][4];
        #pragma unroll
        for (int ct = 0; ct < 2; ++ct) {
            int col = wv * 32 + 2 * ln + ct;
            #pragma unroll
            for (int kk = 0; kk < 4; ++kk)
                bfr[ct][kk] = *(const bf16x8*)&Wb[col * 128 + kk * 32 + q * 8];
        }

        // ---- main MFMA: wave -> 32 cols, rows all 64 (4 tiles of 16)
        f32x4 acc[4][2];
        #pragma unroll
        for (int rt = 0; rt < 4; ++rt)
            #pragma unroll
            for (int ct = 0; ct < 2; ++ct) acc[rt][ct] = (f32x4){0.f, 0.f, 0.f, 0.f};

        #pragma unroll
        for (int rt = 0; rt < 4; ++rt)
            #pragma unroll
            for (int kk = 0; kk < 4; ++kk) {
                acc[rt][0] = __builtin_amdgcn_mfma_f32_16x16x32_bf16(afr[rt][kk], bfr[0][kk], acc[rt][0], 0, 0, 0);
                acc[rt][1] = __builtin_amdgcn_mfma_f32_16x16x32_bf16(afr[rt][kk], bfr[1][kk], acc[rt][1], 0, 0, 0);
            }

        // ---- e = A * wa  (one wave per b, balanced: wv == b%4)
        if (wv == (b & 3)) {
            bf16x8 wz[4];
            #pragma unroll
            for (int kk = 0; kk < 4; ++kk) {
                bf16x8 z = {0, 0, 0, 0, 0, 0, 0, 0};
                if (ln == 0) z = *(const bf16x8*)&wab[b * 128 + kk * 32 + q * 8];
                wz[kk] = z;
            }
            float* e_arr = (t == 0) ? e_center : (t == 1) ? e_int : e_nh;
            #pragma unroll
            for (int rt = 0; rt < 4; ++rt) {
                f32x4 ae = (f32x4){0.f, 0.f, 0.f, 0.f};
                #pragma unroll
                for (int kk = 0; kk < 4; ++kk)
                    ae = __builtin_amdgcn_mfma_f32_16x16x32_bf16(afr[rt][kk], wz[kk], ae, 0, 0, 0);
                if (ln == 0) {
                    #pragma unroll
                    for (int rg = 0; rg < 4; ++rg) {
                        int gr = m_base + rt * 16 + q * 4 + rg;
                        if (gr < N_V) e_arr[h * N_V + gr] = ae[rg];
                    }
                }
            }
        }

        // ---- stores: thread owns adjacent cols c0, c0+1.
        if (t == 0) {
            #pragma unroll
            for (int rt = 0; rt < 4; ++rt)
                #pragma unroll
                for (int rg = 0; rg < 4; ++rg) {
                    int gr = m_base + rt * 16 + q * 4 + rg;
                    if (gr >= N_V) continue;
                    float2 v = make_float2(acc[rt][0][rg], acc[rt][1][rg]);
                    *(float2*)&out[(size_t)gr * 384 + h * 128 + c0] = v;
                }
        } else {
            unsigned short* Vside = (t == 1) ? Vint : Vnh;
            #pragma unroll
            for (int rt = 0; rt < 4; ++rt)
                #pragma unroll
                for (int rg = 0; rg < 4; ++rg) {
                    int gr = m_base + rt * 16 + q * 4 + rg;
                    if (gr >= N_V) continue;
                    uint32_t pk = (uint32_t)f2bf(acc[rt][0][rg]) |
                                  ((uint32_t)f2bf(acc[rt][1][rg]) << 16);
                    *(uint32_t*)&Vside[((size_t)h * N_V + gr) * 128 + c0] = pk;
                }
        }
    }
}

// ---------------------------------------------------------------------------
// Kernel 3: attention (unchanged). One wave per vertex, 4 groups x 16 lanes,
// dwordx4 row gathers, folded alpha/norm, fused bias+ReLU epilogue.
// ---------------------------------------------------------------------------
__global__ __launch_bounds__(256) void attn_kernel(
    const int* __restrict__ nh_idx, const int* __restrict__ int_idx,
    const float* __restrict__ nh_edge, const float* __restrict__ int_edge,
    const float* __restrict__ bv,
    const unsigned short* __restrict__ Vint, const unsigned short* __restrict__ Vnh,
    const float* __restrict__ e_center, const float* __restrict__ e_int,
    const float* __restrict__ e_nh,
    float* __restrict__ out) {
    const int wv   = threadIdx.x >> 6;
    const int lane = threadIdx.x & 63;
    const int n    = blockIdx.x * 4 + wv;
    if (n >= N_V) return;
    const int g  = lane >> 4;
    const int gl = lane & 15;

    const bool part = (g <= 1) && (gl < M_DIM);
    int jm = -1; float wm = 0.f;
    if (part) {
        const int*   idx = (g == 0) ? int_idx  : nh_idx;
        const float* ed  = (g == 0) ? int_edge : nh_edge;
        jm = idx[n * M_DIM + gl];
        wm = ed[n * M_DIM + gl];
    }
    const bool  valid = part && (jm >= 0);
    const int   jc    = valid ? jm : 0;
    const float vfl   = valid ? 1.f : 0.f;

    #pragma unroll
    for (int h = 0; h < H_DIM; ++h) {
        float ec = e_center[h * N_V + n];

        float l = -3.0e38f;
        if (part) {
            const float* es = (g == 0) ? (e_int + (size_t)h * N_V)
                                       : (e_nh  + (size_t)h * N_V);
            float e = es[jc];
            l = valid ? (e + ec) * wm : 0.f;
        }
        float mx = l;
        #pragma unroll
        for (int off = 1; off < 16; off <<= 1) mx = fmaxf(mx, __shfl_xor(mx, off, 64));
        float ex = part ? __expf(l - mx) : 0.f;
        float sv = ex, cf = vfl;
        #pragma unroll
        for (int off = 1; off < 16; off <<= 1) {
            sv += __shfl_xor(sv, off, 64);
            cf += __shfl_xor(cf, off, 64);
        }
        float alphap = 0.f;
        if (valid) alphap = ex / (sv * fmaxf(cf, 1.f));

        const unsigned short* Vb = (g < 2) ? (Vint + (size_t)h * N_V * 128)
                                           : (Vnh  + (size_t)h * N_V * 128);
        const int src_base = (g < 2 ? 0 : 16) + (g & 1) * 5;
        float acc[8] = {0.f, 0.f, 0.f, 0.f, 0.f, 0.f, 0.f, 0.f};
        #pragma unroll
        for (int i = 0; i < 5; ++i) {
            int   src = src_base + i;
            int   j   = __shfl(jc, src, 64);
            float al  = __shfl(alphap, src, 64);
            uint4 pv  = *(const uint4*)&Vb[(size_t)j * 128 + gl * 8];
            uint32_t w4[4] = {pv.x, pv.y, pv.z, pv.w};
            #pragma unroll
            for (int c = 0; c < 4; ++c) {
                union { uint32_t u; float f; } lo, hi;
                lo.u = w4[c] << 16;
                hi.u = w4[c] & 0xffff0000u;
                acc[2 * c]     += al * lo.f;
                acc[2 * c + 1] += al * hi.f;
            }
        }
        #pragma unroll
        for (int c = 0; c < 8; ++c) {
            acc[c] += __shfl_xor(acc[c], 16, 64);
            acc[c] += __shfl_xor(acc[c], 32, 64);
        }
        if (g < 2) {
            size_t o = (size_t)n * 384 + h * 128 + gl * 8 + g * 4;
            float4 zc = *(const float4*)&out[o];
            float4 bb = *(const float4*)&bv[h * 128 + gl * 8 + g * 4];
            float4 zn;
            if (g == 0) zn = make_float4(acc[0], acc[1], acc[2], acc[3]);
            else        zn = make_float4(acc[4], acc[5], acc[6], acc[7]);
            float4 r;
            r.x = fmaxf(zc.x + zn.x + bb.x, 0.f);
            r.y = fmaxf(zc.y + zn.y + bb.y, 0.f);
            r.z = fmaxf(zc.z + zn.z + bb.z, 0.f);
            r.w = fmaxf(zc.w + zn.w + bb.w, 0.f);
            *(float4*)&out[o] = r;
        }
    }
}

// ---------------------------------------------------------------------------
extern "C" void kernel_launch(void* const* d_in, const int* in_sizes, int n_in,
                              void* d_out, int out_size, void* d_ws, size_t ws_size,
                              hipStream_t stream) {
    const float* vertices    = (const float*)d_in[0];
    const int*   nh_indices  = (const int*)d_in[1];
    const int*   int_indices = (const int*)d_in[2];
    const float* nh_edges    = (const float*)d_in[3];
    const float* int_edges   = (const float*)d_in[4];
    // d_in[5] is_int: unused by the reference
    const float* Wvc     = (const float*)d_in[6];
    const float* bv      = (const float*)d_in[7];
    const float* Wvn_int = (const float*)d_in[8];
    const float* Wvn_nh  = (const float*)d_in[9];
    const float* a       = (const float*)d_in[10];
    float* out = (float*)d_out;

    char* ws = (char*)d_ws;
    size_t off = 0;
    unsigned short* Wt = (unsigned short*)(ws + off);
    off += (size_t)WTOT * 2;                  off = (off + 255) & ~(size_t)255;
    unsigned short* wab = (unsigned short*)(ws + off);
    off += (size_t)WACT * 2;                  off = (off + 255) & ~(size_t)255;
    unsigned short* Xb = (unsigned short*)(ws + off);
    off += (size_t)N_V * 128 * 2;             off = (off + 255) & ~(size_t)255;
    unsigned short* Vint = (unsigned short*)(ws + off);
    off += (size_t)H_DIM * N_V * 128 * 2;     off = (off + 255) & ~(size_t)255;
    unsigned short* Vnh = (unsigned short*)(ws + off);
    off += (size_t)H_DIM * N_V * 128 * 2;     off = (off + 255) & ~(size_t)255;
    float* e_center = (float*)(ws + off);
    off += (size_t)H_DIM * N_V * 4;           off = (off + 255) & ~(size_t)255;
    float* e_int = (float*)(ws + off);
    off += (size_t)H_DIM * N_V * 4;           off = (off + 255) & ~(size_t)255;
    float* e_nh = (float*)(ws + off);
    off += (size_t)H_DIM * N_V * 4;

    int prep_threads = WTOT + XCH + WACT;
    prep<<<(prep_threads + 255) / 256, 256, 0, stream>>>(
        Wvc, Wvn_int, Wvn_nh, vertices, a, Wt, Xb, wab);

    gemm_kernel<<<(N_V + 63) / 64, 256, 0, stream>>>(Xb, Wt, wab, out, Vint, Vnh,
                                                     e_center, e_int, e_nh);

    attn_kernel<<<(N_V + 3) / 4, 256, 0, stream>>>(nh_indices, int_indices,
                                                   nh_edges, int_edges, bv,
                                                   Vint, Vnh, e_center, e_int,
                                                   e_nh, out);
}

// Round 6
// 283.053 us; speedup vs baseline: 1.1522x; 1.1522x over previous
//
#include <hip/hip_runtime.h>
#include <stdint.h>

#define N_V 50000
#define F_DIM 128
#define K_DIM 128
#define H_DIM 3
#define M_DIM 10

using bf16x8 = __attribute__((ext_vector_type(8))) short;  // 8 bf16 = 4 VGPRs
using f32x4  = __attribute__((ext_vector_type(4))) float;

__device__ inline unsigned short f2bf(float f) {
    union { float f; uint32_t u; } v; v.f = f;
    uint32_t u = v.u;
    u += 0x7fffu + ((u >> 16) & 1u);   // round-to-nearest-even
    return (unsigned short)(u >> 16);
}

#define LDS_AS __attribute__((address_space(3)))
__device__ inline void gl2lds16(const void* g, void* l) {
    __builtin_amdgcn_global_load_lds(
        (const __attribute__((address_space(1))) unsigned int*)g,
        (LDS_AS unsigned int*)l, 16, 0, 0);
}

// ---------------------------------------------------------------------------
// Kernel 1 (prep): three segments.
//  a) weights (H,F,K) fp32 -> Wt[b][k][f] bf16 (f contiguous)
//  b) X fp32 -> Xb bf16 row-major
//  c) wa[b][f] = sum_col W_b[f,col] * a_vec_b[col]  -> bf16  (for e = X*wa)
// ---------------------------------------------------------------------------
#define WTOT (9 * 128 * 128)
#define XCH  (N_V * 16)          /* 8-element chunks of X */
#define WACT (9 * 128)

__global__ void prep(const float* __restrict__ Wvc,
                     const float* __restrict__ Wvn_int,
                     const float* __restrict__ Wvn_nh,
                     const float* __restrict__ X,
                     const float* __restrict__ a,
                     unsigned short* __restrict__ Wt,
                     unsigned short* __restrict__ Xb,
                     unsigned short* __restrict__ wab) {
    int idx = blockIdx.x * 256 + threadIdx.x;
    if (idx < WTOT) {
        int b   = idx >> 14;
        int rem = idx & 16383;
        int k = rem >> 7;
        int f = rem & 127;
        int h = b / 3, t = b - 3 * h;
        const float* src = (t == 0) ? Wvc : (t == 1) ? Wvn_int : Wvn_nh;
        Wt[idx] = f2bf(src[(h * 128 + f) * 128 + k]);
        return;
    }
    int xi = idx - WTOT;             // chunk of 8 floats of X
    if (xi < XCH) {
        const float4* Xv = (const float4*)X;
        float4 v0 = Xv[xi * 2];
        float4 v1 = Xv[xi * 2 + 1];
        uint4 o;
        o.x = (uint32_t)f2bf(v0.x) | ((uint32_t)f2bf(v0.y) << 16);
        o.y = (uint32_t)f2bf(v0.z) | ((uint32_t)f2bf(v0.w) << 16);
        o.z = (uint32_t)f2bf(v1.x) | ((uint32_t)f2bf(v1.y) << 16);
        o.w = (uint32_t)f2bf(v1.z) | ((uint32_t)f2bf(v1.w) << 16);
        *(uint4*)&Xb[(size_t)xi * 8] = o;
        return;
    }
    int wi = xi - XCH;               // wa entry
    if (wi < WACT) {
        int b = wi >> 7, f = wi & 127;
        int h = b / 3, t = b - 3 * h;
        const float* src = (t == 0) ? Wvc : (t == 1) ? Wvn_int : Wvn_nh;
        const float4* wrow = (const float4*)&src[(h * 128 + f) * 128];
        const float4* av   = (const float4*)&a[h * 256 + (t == 0 ? 128 : 0)];
        float acc = 0.f;
        #pragma unroll 8
        for (int c = 0; c < 32; ++c) {
            float4 w = wrow[c], x = av[c];
            acc += w.x * x.x + w.y * x.y + w.z * x.z + w.w * x.w;
        }
        wab[b * 128 + f] = f2bf(acc);
    }
}

// ---------------------------------------------------------------------------
// Kernel 2: MFMA GEMM (R4 structure — known best). Grid = (ceil(N/64), 9).
// Block = 256 thr (4 waves). A staged via global_load_lds (16B, XOR-16
// swizzle); B direct-from-global in registers; pack-2 stores; e = A*wa MFMA.
// ---------------------------------------------------------------------------
__global__ __launch_bounds__(256, 3) void gemm_kernel(
    const unsigned short* __restrict__ Xb,  // N_V x 128 bf16
    const unsigned short* __restrict__ Wt,  // 9 x 128(k) x 128(f) bf16
    const unsigned short* __restrict__ wab, // 9 x 128 bf16
    float* __restrict__ out,                // N_V x 384
    unsigned short* __restrict__ Vint,      // H*N_V*128 bf16
    unsigned short* __restrict__ Vnh,       // H*N_V*128 bf16
    float* __restrict__ e_center,           // H*N_V
    float* __restrict__ e_int,
    float* __restrict__ e_nh) {
    __shared__ unsigned short As[64 * 128];   // 16 KB, swizzled

    const int tid    = threadIdx.x;
    const int b      = blockIdx.y;
    const int h      = b / 3;
    const int t      = b - 3 * h;
    const int m_base = blockIdx.x * 64;
    const int wv     = tid >> 6;
    const int lane   = tid & 63;
    const int q      = lane >> 4;
    const int ln     = lane & 15;

    // ---- B fragments (direct global, L2-hot). col = wv*32 + 2*ln + ct.
    const unsigned short* Wb = Wt + b * 16384;
    bf16x8 bfr[2][4];
    #pragma unroll
    for (int ct = 0; ct < 2; ++ct) {
        int col = wv * 32 + 2 * ln + ct;
        #pragma unroll
        for (int kk = 0; kk < 4; ++kk)
            bfr[ct][kk] = *(const bf16x8*)&Wb[col * 128 + kk * 32 + q * 8];
    }

    // ---- A staging: 1024 chunks of 16B. physical chunk p of row r holds
    // logical chunk p ^ (r & 15); dest = wave-uniform base + lane*16.
    #pragma unroll
    for (int it = 0; it < 4; ++it) {
        int c16 = it * 256 + tid;       // 0..1023
        int r   = c16 >> 4;
        int p   = c16 & 15;
        int lch = p ^ (r & 15);
        int gr  = m_base + r;
        if (gr >= N_V) gr = 0;          // clamp (stores guarded later)
        gl2lds16(Xb + (size_t)gr * 128 + lch * 8, &As[c16 * 8]);
    }
    __syncthreads();

    // ---- main MFMA: wave w -> 32 cols, rows all 64 (4 tiles of 16)
    f32x4 acc[4][2];
    #pragma unroll
    for (int rt = 0; rt < 4; ++rt)
        #pragma unroll
        for (int ct = 0; ct < 2; ++ct) acc[rt][ct] = (f32x4){0.f, 0.f, 0.f, 0.f};

    #pragma unroll
    for (int rt = 0; rt < 4; ++rt) {
        int r = rt * 16 + ln;
        #pragma unroll
        for (int kk = 0; kk < 4; ++kk) {
            int p = (kk * 4 + q) ^ ln;   // unswizzle (r & 15 == ln)
            bf16x8 afr = *(const bf16x8*)&As[r * 128 + p * 8];
            acc[rt][0] = __builtin_amdgcn_mfma_f32_16x16x32_bf16(afr, bfr[0][kk], acc[rt][0], 0, 0, 0);
            acc[rt][1] = __builtin_amdgcn_mfma_f32_16x16x32_bf16(afr, bfr[1][kk], acc[rt][1], 0, 0, 0);
        }
    }

    // ---- e = A * wa  (wave 0 only; B col 0 = wa, cols 1..15 = 0)
    if (wv == 0) {
        bf16x8 wz[4];
        #pragma unroll
        for (int kk = 0; kk < 4; ++kk) {
            bf16x8 z = {0, 0, 0, 0, 0, 0, 0, 0};
            if (ln == 0) z = *(const bf16x8*)&wab[b * 128 + kk * 32 + q * 8];
            wz[kk] = z;
        }
        float* e_arr = (t == 0) ? e_center : (t == 1) ? e_int : e_nh;
        #pragma unroll
        for (int rt = 0; rt < 4; ++rt) {
            int r = rt * 16 + ln;
            f32x4 ae = (f32x4){0.f, 0.f, 0.f, 0.f};
            #pragma unroll
            for (int kk = 0; kk < 4; ++kk) {
                int p = (kk * 4 + q) ^ ln;
                bf16x8 afr = *(const bf16x8*)&As[r * 128 + p * 8];
                ae = __builtin_amdgcn_mfma_f32_16x16x32_bf16(afr, wz[kk], ae, 0, 0, 0);
            }
            if (ln == 0) {
                #pragma unroll
                for (int rg = 0; rg < 4; ++rg) {
                    int gr = m_base + rt * 16 + q * 4 + rg;
                    if (gr < N_V) e_arr[h * N_V + gr] = ae[rg];
                }
            }
        }
    }

    // ---- stores: thread owns adjacent cols c0 = wv*32 + 2*ln, c0+1.
    const int c0 = wv * 32 + 2 * ln;
    if (t == 0) {
        #pragma unroll
        for (int rt = 0; rt < 4; ++rt)
            #pragma unroll
            for (int rg = 0; rg < 4; ++rg) {
                int gr = m_base + rt * 16 + q * 4 + rg;
                if (gr >= N_V) continue;
                float2 v = make_float2(acc[rt][0][rg], acc[rt][1][rg]);
                *(float2*)&out[(size_t)gr * 384 + h * 128 + c0] = v;
            }
    } else {
        unsigned short* Vside = (t == 1) ? Vint : Vnh;
        #pragma unroll
        for (int rt = 0; rt < 4; ++rt)
            #pragma unroll
            for (int rg = 0; rg < 4; ++rg) {
                int gr = m_base + rt * 16 + q * 4 + rg;
                if (gr >= N_V) continue;
                uint32_t pk = (uint32_t)f2bf(acc[rt][0][rg]) |
                              ((uint32_t)f2bf(acc[rt][1][rg]) << 16);
                *(uint32_t*)&Vside[((size_t)h * N_V + gr) * 128 + c0] = pk;
            }
    }
}

// ---------------------------------------------------------------------------
// Kernel 3: attention for ONE head (per-head dispatch keeps the 25.6 MB
// V working set L3/L2-resident). One wave per vertex, 4 groups x 16 lanes,
// dwordx4 row gathers, folded alpha/norm, fused bias+ReLU epilogue.
// All V/e pointers are pre-offset to this head; hoff = h*128.
// ---------------------------------------------------------------------------
__global__ __launch_bounds__(256) void attn_head_kernel(
    const int* __restrict__ nh_idx, const int* __restrict__ int_idx,
    const float* __restrict__ nh_edge, const float* __restrict__ int_edge,
    const float* __restrict__ bv_h,
    const unsigned short* __restrict__ Vint_h,
    const unsigned short* __restrict__ Vnh_h,
    const float* __restrict__ ec_h, const float* __restrict__ ei_h,
    const float* __restrict__ en_h,
    float* __restrict__ out, int hoff) {
    const int wv   = threadIdx.x >> 6;
    const int lane = threadIdx.x & 63;
    const int n    = blockIdx.x * 4 + wv;
    if (n >= N_V) return;
    const int g  = lane >> 4;
    const int gl = lane & 15;

    const bool part = (g <= 1) && (gl < M_DIM);
    int jm = -1; float wm = 0.f;
    if (part) {
        const int*   idx = (g == 0) ? int_idx  : nh_idx;
        const float* ed  = (g == 0) ? int_edge : nh_edge;
        jm = idx[n * M_DIM + gl];
        wm = ed[n * M_DIM + gl];
    }
    const bool  valid = part && (jm >= 0);
    const int   jc    = valid ? jm : 0;
    const float vfl   = valid ? 1.f : 0.f;

    float ec = ec_h[n];

    // ---- logits (lanes 0-9: int, 16-25: nh). masked entries logit = 0.
    float l = -3.0e38f;
    if (part) {
        const float* es = (g == 0) ? ei_h : en_h;
        float e = es[jc];
        l = valid ? (e + ec) * wm : 0.f;
    }
    float mx = l;
    #pragma unroll
    for (int off = 1; off < 16; off <<= 1) mx = fmaxf(mx, __shfl_xor(mx, off, 64));
    float ex = part ? __expf(l - mx) : 0.f;
    float sv = ex, cf = vfl;
    #pragma unroll
    for (int off = 1; off < 16; off <<= 1) {
        sv += __shfl_xor(sv, off, 64);
        cf += __shfl_xor(cf, off, 64);
    }
    float alphap = 0.f;
    if (valid) alphap = ex / (sv * fmaxf(cf, 1.f));

    // ---- gather: group g handles 5 rows of its branch
    const unsigned short* Vb = (g < 2) ? Vint_h : Vnh_h;
    const int src_base = (g < 2 ? 0 : 16) + (g & 1) * 5;
    float acc[8] = {0.f, 0.f, 0.f, 0.f, 0.f, 0.f, 0.f, 0.f};
    #pragma unroll
    for (int i = 0; i < 5; ++i) {
        int   src = src_base + i;
        int   j   = __shfl(jc, src, 64);
        float al  = __shfl(alphap, src, 64);
        uint4 pv  = *(const uint4*)&Vb[(size_t)j * 128 + gl * 8];
        uint32_t w4[4] = {pv.x, pv.y, pv.z, pv.w};
        #pragma unroll
        for (int c = 0; c < 4; ++c) {
            union { uint32_t u; float f; } lo, hi;
            lo.u = w4[c] << 16;
            hi.u = w4[c] & 0xffff0000u;
            acc[2 * c]     += al * lo.f;
            acc[2 * c + 1] += al * hi.f;
        }
    }
    #pragma unroll
    for (int c = 0; c < 8; ++c) {
        acc[c] += __shfl_xor(acc[c], 16, 64);
        acc[c] += __shfl_xor(acc[c], 32, 64);
    }
    if (g < 2) {
        size_t o = (size_t)n * 384 + hoff + gl * 8 + g * 4;
        float4 zc = *(const float4*)&out[o];
        float4 bb = *(const float4*)&bv_h[gl * 8 + g * 4];
        float4 zn;
        if (g == 0) zn = make_float4(acc[0], acc[1], acc[2], acc[3]);
        else        zn = make_float4(acc[4], acc[5], acc[6], acc[7]);
        float4 r;
        r.x = fmaxf(zc.x + zn.x + bb.x, 0.f);
        r.y = fmaxf(zc.y + zn.y + bb.y, 0.f);
        r.z = fmaxf(zc.z + zn.z + bb.z, 0.f);
        r.w = fmaxf(zc.w + zn.w + bb.w, 0.f);
        *(float4*)&out[o] = r;
    }
}

// ---------------------------------------------------------------------------
extern "C" void kernel_launch(void* const* d_in, const int* in_sizes, int n_in,
                              void* d_out, int out_size, void* d_ws, size_t ws_size,
                              hipStream_t stream) {
    const float* vertices    = (const float*)d_in[0];
    const int*   nh_indices  = (const int*)d_in[1];
    const int*   int_indices = (const int*)d_in[2];
    const float* nh_edges    = (const float*)d_in[3];
    const float* int_edges   = (const float*)d_in[4];
    // d_in[5] is_int: unused by the reference
    const float* Wvc     = (const float*)d_in[6];
    const float* bv      = (const float*)d_in[7];
    const float* Wvn_int = (const float*)d_in[8];
    const float* Wvn_nh  = (const float*)d_in[9];
    const float* a       = (const float*)d_in[10];
    float* out = (float*)d_out;

    char* ws = (char*)d_ws;
    size_t off = 0;
    unsigned short* Wt = (unsigned short*)(ws + off);
    off += (size_t)WTOT * 2;                  off = (off + 255) & ~(size_t)255;
    unsigned short* wab = (unsigned short*)(ws + off);
    off += (size_t)WACT * 2;                  off = (off + 255) & ~(size_t)255;
    unsigned short* Xb = (unsigned short*)(ws + off);
    off += (size_t)N_V * 128 * 2;             off = (off + 255) & ~(size_t)255;
    unsigned short* Vint = (unsigned short*)(ws + off);
    off += (size_t)H_DIM * N_V * 128 * 2;     off = (off + 255) & ~(size_t)255;
    unsigned short* Vnh = (unsigned short*)(ws + off);
    off += (size_t)H_DIM * N_V * 128 * 2;     off = (off + 255) & ~(size_t)255;
    float* e_center = (float*)(ws + off);
    off += (size_t)H_DIM * N_V * 4;           off = (off + 255) & ~(size_t)255;
    float* e_int = (float*)(ws + off);
    off += (size_t)H_DIM * N_V * 4;           off = (off + 255) & ~(size_t)255;
    float* e_nh = (float*)(ws + off);
    off += (size_t)H_DIM * N_V * 4;

    int prep_threads = WTOT + XCH + WACT;
    prep<<<(prep_threads + 255) / 256, 256, 0, stream>>>(
        Wvc, Wvn_int, Wvn_nh, vertices, a, Wt, Xb, wab);

    dim3 grid_g((N_V + 63) / 64, 9);
    gemm_kernel<<<grid_g, 256, 0, stream>>>(Xb, Wt, wab, out, Vint, Vnh,
                                            e_center, e_int, e_nh);

    for (int h = 0; h < H_DIM; ++h) {
        attn_head_kernel<<<(N_V + 3) / 4, 256, 0, stream>>>(
            nh_indices, int_indices, nh_edges, int_edges,
            bv + h * 128,
            Vint + (size_t)h * N_V * 128,
            Vnh  + (size_t)h * N_V * 128,
            e_center + (size_t)h * N_V,
            e_int    + (size_t)h * N_V,
            e_nh     + (size_t)h * N_V,
            out, h * 128);
    }
}